// Round 7
// baseline (279.574 us; speedup 1.0000x reference)
//
#include <hip/hip_runtime.h>
#include <hip/hip_bf16.h>

// Butterfly structure (BASE=3, FACTOR=0, n=27):
//   mask[s,t] != 0  iff  floor(s1/3)==floor(t1/3) && floor(s2/3)==floor(t2/3),
//   s = 27*s1 + s2.  81 groups g=(G1,G2); group members: 81*G1 + 27*i + 3*G2 + j.
//   attn packed: attn[g*81 + ls*9 + lt], g = 9*G1+G2, ls/lt = 3i+j.
// Dtypes: inputs fp32, output fp32.
//
// Measured history (mlp kernel, all ~identical):
//   r0 LDS-stage + scatter store:   88-92 us   (occ 55%, VALU 21%)
//   r4 direct dwordx3 shallow:      ~90 us
//   r5 direct dwordx3 8-deep burst: 86.8 us    (occ 26% — HALF of r0, same perf)
//   r6 all-coalesced dwordx4 LDS:   85.4-88 us (occ 37%, VALU 26%)
//   r1/r2 persistent global_load_lds lockstep: 253 us, 4.2x traffic. Dead end.
//   fillBufferAligned in-run: 6.7 TB/s. m13 copy: 6.3 TB/s.
// Eliminated: HBM bytes, VALU, LDS conflicts, occupancy, load depth, VMEM
// granularity/coalescing. Remaining arithmetic: per-CU pipe budgets VALU~22us
// + LDS~23us + VMEM~20us + mem-wait ~ sum = 86us (measured) vs max = ~40us
// if overlapped. All variants share sequential phases with nothing in flight
// during compute. This round: intra-block software pipeline (T14 issue-early
// / write-late), double-buffered LDS, one barrier per tile, direct scatter
// stores (proven traffic-clean) interleaved with compute.

__device__ __forceinline__ float gelu_f(float v) {
    // tanh-form gelu; |err| < ~7e-4, threshold 1.44e-2 (measured absmax 3.9e-3).
    float u2 = v * v;
    float z = -1.5957691216f * v * fmaf(0.044715f, u2, 1.0f);
    float e = __expf(z);
    return v * __builtin_amdgcn_rcpf(1.0f + e);
}

// ---------------- Kernel 0: zero attn scratch (ws is poisoned 0xAA) --------
__global__ void attn_zero_kernel(float* __restrict__ attn) {
    int i = blockIdx.x * 256 + threadIdx.x;
    if (i < 81 * 81) attn[i] = 0.0f;
}

// ---------------- Kernel 1: block-sparse attn = (w1^T . w2^T) .* mask ------
// Unchanged (measured: a few us, not on the critical path).
#define CH 108   // 27 chunks * 108 = 2916

__global__ __launch_bounds__(256) void bfly_attn_kernel(
        const float* __restrict__ w1,   // [2916, 729]
        const float* __restrict__ w2,   // [729, 2916]
        float* __restrict__ attn)       // [81*81], pre-zeroed
{
    const int G1    = blockIdx.x % 9;
    const int d0    = (blockIdx.x / 9) * CH;
    const int tid   = threadIdx.x;

    __shared__ float ws1[CH * 81];      // [dl][c]   34992 B
    __shared__ float ws2[81 * CH];      // [tl][dl]  34992 B

    for (int i = tid; i < CH * 81; i += 256) {
        int dl = i / 81, c = i % 81;
        ws1[i] = w1[(d0 + dl) * 729 + 81 * G1 + c];
    }
    for (int i = tid; i < 81 * CH; i += 256) {
        int tl = i / CH, dl = i % CH;
        ws2[i] = w2[(81 * G1 + tl) * 2916 + d0 + dl];
    }
    __syncthreads();

    if (tid < 243) {
        const int G2  = tid / 27;
        const int ls  = (tid % 27) / 3;
        const int lt0 = (tid % 3) * 3;
        const int s_l = 27 * (ls / 3) + 3 * G2 + (ls % 3);
        int t_l[3];
        #pragma unroll
        for (int j = 0; j < 3; ++j) {
            int lt = lt0 + j;
            t_l[j] = 27 * (lt / 3) + 3 * G2 + (lt % 3);
        }

        float a0 = 0.f, a1 = 0.f, a2 = 0.f;
        for (int dl = 0; dl < CH; ++dl) {
            float av = ws1[dl * 81 + s_l];
            a0 = fmaf(av, ws2[t_l[0] * CH + dl], a0);
            a1 = fmaf(av, ws2[t_l[1] * CH + dl], a1);
            a2 = fmaf(av, ws2[t_l[2] * CH + dl], a2);
        }

        const int g = 9 * G1 + G2;
        float* dst = &attn[g * 81 + ls * 9 + lt0];
        atomicAdd(dst + 0, a0);
        atomicAdd(dst + 1, a1);
        atomicAdd(dst + 2, a2);
    }
}

// ---------------- Kernel 2: out = gelu(x @ attn_blocksparse + b2) ----------
// Software-pipelined short-lived blocks:
//   TILE=4 rows/tile, TPB=4 tiles/block, grid 3072 (NOT persistent).
//   LDS: 2 x 11664 B double buffer -> 6 blocks/CU.
//   Per tile: sync -> issue next tile's global loads into regs (no wait)
//             -> compute cur tile from LDS + scatter-store results
//             -> ds_write staged regs into next buffer (vmcnt lands here,
//                after ~2us of compute >> HBM latency).
//   Loads in flight during ~75% of block lifetime; stores interleaved.
#define TILE 4
#define TPB  4
#define NBLK 3072           // 3072 * 16 rows = 49152
#define TV4  (TILE * 729 / 4)   // 729 uint4 per tile

struct f3 { float x, y, z; };

__global__ __launch_bounds__(256) void bfly_mlp_kernel(
        const float* __restrict__ xg,    // [49152, 729] fp32
        const float* __restrict__ attn,  // [81*81] fp32 (ws)
        const float* __restrict__ b2g,   // [729] fp32
        float* __restrict__ outg)        // [49152, 729] fp32
{
    __shared__ float xs[2][TILE * 729];  // 2 x 11664 B

    const int tid = threadIdx.x;
    const bool active = (tid < 243);

    // Per-thread weights (L2-hot after first blocks; overlaps prologue loads).
    float a[9][3], bias[3];
    int tb = 0, sb = 0;
    if (active) {
        const int t1 = tid / 9;           // 0..26
        const int G2 = tid % 9;           // 0..8
        const int G1 = t1 / 3;
        const int li = t1 % 3;
        tb = 3 * tid;                     // contiguous output triplet
        sb = 81 * G1 + 3 * G2;            // x column base (3 triplets @ 27)
        const int g  = 9 * G1 + G2;
        #pragma unroll
        for (int ls = 0; ls < 9; ++ls) {
            f3 v = *reinterpret_cast<const f3*>(&attn[g * 81 + ls * 9 + 3 * li]);
            a[ls][0] = v.x; a[ls][1] = v.y; a[ls][2] = v.z;
        }
        f3 v = *reinterpret_cast<const f3*>(&b2g[tb]);
        bias[0] = v.x; bias[1] = v.y; bias[2] = v.z;
    }

    const long long rowbase = (long long)blockIdx.x * (TILE * TPB);
    const uint4* __restrict__ xsrc = (const uint4*)(xg + rowbase * 729);

    // Staged-load registers for one tile: up to 3 uint4 per thread.
    // (729 uint4/tile; threads 0..216 carry a 3rd element.)
    uint4 g0, g1, g2;
    const bool has2 = (tid + 512) < TV4;

    // ---- prologue: load tile 0 into regs, write to buf 0 ----
    {
        const uint4* s = xsrc;                  // tile 0
        g0 = s[tid];
        g1 = s[tid + 256];
        if (has2) g2 = s[tid + 512];
        uint4* d = (uint4*)xs[0];
        d[tid] = g0;
        d[tid + 256] = g1;
        if (has2) d[tid + 512] = g2;
    }

    int cur = 0;
    for (int t = 0; t < TPB; ++t) {
        __syncthreads();   // buf[cur] (written last iteration / prologue) ready

        // Issue next tile's global loads NOW (no wait) — in flight during
        // all of this tile's compute.
        if (t + 1 < TPB) {
            const uint4* s = xsrc + (t + 1) * TV4;
            g0 = s[tid];
            g1 = s[tid + 256];
            if (has2) g2 = s[tid + 512];
        }

        if (active) {
            const float* xb = xs[cur];
            #pragma unroll
            for (int r = 0; r < TILE; ++r) {
                const float* xr = xb + r * 729 + sb;
                float xv[9];
                #pragma unroll
                for (int i2 = 0; i2 < 3; ++i2)
                    #pragma unroll
                    for (int j2 = 0; j2 < 3; ++j2)
                        xv[3 * i2 + j2] = xr[27 * i2 + j2];

                float acc0 = bias[0], acc1 = bias[1], acc2 = bias[2];
                #pragma unroll
                for (int ls = 0; ls < 9; ++ls) {
                    acc0 = fmaf(xv[ls], a[ls][0], acc0);
                    acc1 = fmaf(xv[ls], a[ls][1], acc1);
                    acc2 = fmaf(xv[ls], a[ls][2], acc2);
                }
                // Direct scatter store, interleaved with compute. r0/r5
                // proved this is traffic-clean (L2 merges to full lines).
                f3 o; o.x = gelu_f(acc0); o.y = gelu_f(acc1); o.z = gelu_f(acc2);
                const long long row = rowbase + (long long)t * TILE + r;
                *reinterpret_cast<f3*>(&outg[row * 729 + tb]) = o;
            }
        }

        // Write staged regs into the other buffer. The compiler's vmcnt
        // wait lands here — after the compute above, latency long hidden.
        if (t + 1 < TPB) {
            uint4* d = (uint4*)xs[cur ^ 1];
            d[tid] = g0;
            d[tid + 256] = g1;
            if (has2) d[tid + 512] = g2;
        }
        cur ^= 1;
    }
}

extern "C" void kernel_launch(void* const* d_in, const int* in_sizes, int n_in,
                              void* d_out, int out_size, void* d_ws, size_t ws_size,
                              hipStream_t stream) {
    const float* x  = (const float*)d_in[0];  // [64,768,729]
    const float* w1 = (const float*)d_in[1];  // [2916,729]
    const float* w2 = (const float*)d_in[2];  // [729,2916]
    const float* b2 = (const float*)d_in[3];  // [729]
    // d_in[4] = sparse_mask: static butterfly structure, never read.

    float* attn = (float*)d_ws;  // 26244 B scratch

    attn_zero_kernel<<<26, 256, 0, stream>>>(attn);
    bfly_attn_kernel<<<9 * 27, 256, 0, stream>>>(w1, w2, attn);

    bfly_mlp_kernel<<<NBLK, 256, 0, stream>>>(x, attn, b2, (float*)d_out);
}